// Round 4
// baseline (220.885 us; speedup 1.0000x reference)
//
#include <hip/hip_runtime.h>

typedef _Float16 f16;
typedef _Float16 f16x8 __attribute__((ext_vector_type(8)));
typedef __fp16   fp16x2 __attribute__((ext_vector_type(2)));
typedef float    f32x16 __attribute__((ext_vector_type(16)));
typedef float    f32x4  __attribute__((ext_vector_type(4)));
typedef unsigned int u32;
typedef unsigned int u32x4 __attribute__((ext_vector_type(4)));

#define NPTS 262144

// ---- packed layout in d_ws (per net, net stride NET_F16 f16) ----
//   L0:   [0      .. 4096)   frag[mt][lane][8]   canonical k = 8*hi+j (K padded, zeros)
//   L1:   [4096   .. 69632)  frag[kt][mt][lane][8]  PERMUTED k (see kphys below)
//   L2:   [69632  .. 135168) frag[kt][mt][lane][8]  PERMUTED k
//   L3:   [135168 .. 143360) frag[kt][lane][8]      PERMUTED k (m = lane&31 < 3)
// PERMUTED k mapping: kphys(kt,hi,j) = 32*(kt>>1) + 16*(kt&1) + (j&3) + 8*(j>>2) + 4*hi
// This equals the C/D layout of the PREVIOUS layer's 32x32 tile, so the epilogue
// needs NO cross-lane exchange: C/D regs pack directly into next-layer B-frags.
// f32 biases at byte BIAS_BYTE, 800 floats/net, packed in C/D order.
#define NET_F16   143360
#define L1_OFF    4096
#define L2_OFF    69632
#define L3_OFF    135168
#define BIAS_BYTE 573440

static __device__ __forceinline__ u32 pkrtz(float a, float b) {
    fp16x2 h = __builtin_amdgcn_cvt_pkrtz(a, b);
    return __builtin_bit_cast(u32, h);
}
// ReLU in f32 then pack (RTZ of nonneg is nonneg -> identical to pack-then-max).
static __device__ __forceinline__ u32 relu_pk(float a, float b) {
    return pkrtz(fmaxf(a, 0.0f), fmaxf(b, 0.0f));
}

// ---------------- weight/bias packing kernel ----------------
__global__ void prep_kernel(
    const float* __restrict__ dW0, const float* __restrict__ db0,
    const float* __restrict__ dW1, const float* __restrict__ db1,
    const float* __restrict__ dW2, const float* __restrict__ db2,
    const float* __restrict__ dW3, const float* __restrict__ db3,
    const float* __restrict__ sW0, const float* __restrict__ sb0,
    const float* __restrict__ sW1, const float* __restrict__ sb1,
    const float* __restrict__ sW2, const float* __restrict__ sb2,
    const float* __restrict__ sW3, const float* __restrict__ sb3,
    f16* __restrict__ wpk, float* __restrict__ bpk)
{
    const int ROWS = 17920;
    int t = blockIdx.x * 256 + threadIdx.x;
    if (t < 2 * ROWS) {
        int net = (t >= ROWS) ? 1 : 0;
        int r = t - net * ROWS;
        const float* W0 = net ? sW0 : dW0;
        const float* W1 = net ? sW1 : dW1;
        const float* W2 = net ? sW2 : dW2;
        const float* W3 = net ? sW3 : dW3;
        int K0 = net ? 8 : 3;
        f16* o = wpk + net * NET_F16;
        if (r < 512) {                                   // L0: canonical slots
            int lane = r & 63;
            int m  = 32 * (r >> 6) + (lane & 31);
            int kb = 8 * (lane >> 5);
            f16* q = o + r * 8;
            #pragma unroll
            for (int j = 0; j < 8; ++j) {
                int k = kb + j;
                q[j] = (f16)((k < K0) ? W0[k * 256 + m] : 0.0f);
            }
        } else if (r < 512 + 8192) {                     // L1: permuted k
            int rr = r - 512;
            int lane = rr & 63;
            int hh = lane >> 5;
            int m  = 32 * ((rr >> 6) & 7) + (lane & 31);
            int kt = rr >> 9;
            f16* q = o + L1_OFF + rr * 8;
            #pragma unroll
            for (int j = 0; j < 8; ++j) {
                int kp = 32 * (kt >> 1) + 16 * (kt & 1) + (j & 3) + 8 * (j >> 2) + 4 * hh;
                q[j] = (f16)W1[kp * 256 + m];
            }
        } else if (r < 512 + 16384) {                    // L2: permuted k
            int rr = r - (512 + 8192);
            int lane = rr & 63;
            int hh = lane >> 5;
            int m  = 32 * ((rr >> 6) & 7) + (lane & 31);
            int kt = rr >> 9;
            f16* q = o + L2_OFF + rr * 8;
            #pragma unroll
            for (int j = 0; j < 8; ++j) {
                int kp = 32 * (kt >> 1) + 16 * (kt & 1) + (j & 3) + 8 * (j >> 2) + 4 * hh;
                q[j] = (f16)W2[kp * 256 + m];
            }
        } else {                                         // L3: permuted k
            int rr = r - (512 + 16384);
            int lane = rr & 63;
            int hh = lane >> 5;
            int m  = lane & 31;
            int kt = rr >> 6;
            f16* q = o + L3_OFF + rr * 8;
            #pragma unroll
            for (int j = 0; j < 8; ++j) {
                int kp = 32 * (kt >> 1) + 16 * (kt & 1) + (j & 3) + 8 * (j >> 2) + 4 * hh;
                q[j] = (f16)((m < 3) ? W3[kp * 3 + m] : 0.0f);
            }
        }
    } else if (t < 2 * ROWS + 1600) {                    // biases (C/D order)
        int tb = t - 2 * ROWS;
        int net = (tb >= 800) ? 1 : 0;
        int i = tb - net * 800;
        float val;
        if (i < 768) {
            int layer = i >> 8;
            const float* bl = net ? (layer == 0 ? sb0 : layer == 1 ? sb1 : sb2)
                                  : (layer == 0 ? db0 : layer == 1 ? db1 : db2);
            int q  = i & 255;
            int rg = q & 15, h = (q >> 4) & 1;
            int m  = 32 * (q >> 5) + (rg & 3) + 8 * (rg >> 2) + 4 * h;
            val = bl[m];
        } else {
            int q  = i - 768;
            int rg = q & 15, h = q >> 4;
            int m  = (rg & 3) + 8 * (rg >> 2) + 4 * h;
            const float* b3 = net ? sb3 : db3;
            val = (m < 3) ? b3[m] : 0.0f;
        }
        bpk[net * 800 + i] = val;
    }
}

// 8 x global_load_lds dwordx4: one 8KB weight chunk (frag[mt][lane], lane-linear).
static __device__ __forceinline__ void dma8(const u32x4* __restrict__ g, u32x4* l, int lane) {
    #pragma unroll
    for (int i = 0; i < 8; ++i)
        __builtin_amdgcn_global_load_lds(
            (const __attribute__((address_space(1))) void*)(g + i * 64 + lane),
            (__attribute__((address_space(3))) void*)(l + i * 64), 16, 0, 0);
}

// 256x256 layer, pt=2: private-dbuf staging, counted vmcnt, no barriers.
template<bool HASNXT>
static __device__ __forceinline__ void layer256(
    const f16* __restrict__ wl, const float* __restrict__ bl, const f16* __restrict__ nxt,
    f32x16 (&acc0)[8], f32x16 (&acc1)[8],
    u32x4 (&xf0)[16], u32x4 (&xf1)[16],
    u32x4* buf0, u32x4* buf1, const int lane, const int hi)
{
    const u32x4* wq = (const u32x4*)wl;
    #pragma unroll
    for (int mt = 0; mt < 8; ++mt) {                     // bias-init both acc sets
        const f32x4* b4 = (const f32x4*)(bl + mt * 32 + hi * 16);
        const f32x4 v0 = b4[0], v1 = b4[1], v2 = b4[2], v3 = b4[3];
        #pragma unroll
        for (int j = 0; j < 4; ++j) {
            acc0[mt][j] = v0[j]; acc0[mt][4 + j] = v1[j]; acc0[mt][8 + j] = v2[j]; acc0[mt][12 + j] = v3[j];
            acc1[mt][j] = v0[j]; acc1[mt][4 + j] = v1[j]; acc1[mt][8 + j] = v2[j]; acc1[mt][12 + j] = v3[j];
        }
    }
    #pragma unroll
    for (int kt = 0; kt < 16; ++kt) {
        if (kt < 15) {                                   // issue next chunk early
            dma8(wq + (kt + 1) * 512, (kt & 1) ? buf0 : buf1, lane);
            asm volatile("s_waitcnt vmcnt(8)" ::: "memory");   // chunk kt landed
        } else if (HASNXT) {                             // prefetch next layer's chunk0
            dma8((const u32x4*)nxt, buf0, lane);
            asm volatile("s_waitcnt vmcnt(8)" ::: "memory");
        } else {
            asm volatile("s_waitcnt vmcnt(0)" ::: "memory");   // full drain (last layer)
        }
        const u32x4* src = (kt & 1) ? buf1 : buf0;
        const f16x8 xA = __builtin_bit_cast(f16x8, xf0[kt]);
        const f16x8 xB = __builtin_bit_cast(f16x8, xf1[kt]);
        #pragma unroll
        for (int mt = 0; mt < 8; ++mt) {
            const f16x8 a = __builtin_bit_cast(f16x8, src[mt * 64 + lane]);
            acc0[mt] = __builtin_amdgcn_mfma_f32_32x32x16_f16(a, xA, acc0[mt], 0, 0, 0);
            acc1[mt] = __builtin_amdgcn_mfma_f32_32x32x16_f16(a, xB, acc1[mt], 0, 0, 0);
        }
    }
}

// Zero-shuffle epilogue: C/D regs -> ReLU -> f16 -> next-layer B-frags directly.
#define EPI() do {                                                           \
    _Pragma("unroll")                                                        \
    for (int mt = 0; mt < 8; ++mt) {                                         \
        _Pragma("unroll")                                                    \
        for (int q = 0; q < 2; ++q) {                                        \
            u32x4 wA, wB;                                                    \
            wA[0] = relu_pk(acc0[mt][8*q+0], acc0[mt][8*q+1]);               \
            wA[1] = relu_pk(acc0[mt][8*q+2], acc0[mt][8*q+3]);               \
            wA[2] = relu_pk(acc0[mt][8*q+4], acc0[mt][8*q+5]);               \
            wA[3] = relu_pk(acc0[mt][8*q+6], acc0[mt][8*q+7]);               \
            xf0[2*mt+q] = wA;                                                \
            wB[0] = relu_pk(acc1[mt][8*q+0], acc1[mt][8*q+1]);               \
            wB[1] = relu_pk(acc1[mt][8*q+2], acc1[mt][8*q+3]);               \
            wB[2] = relu_pk(acc1[mt][8*q+4], acc1[mt][8*q+5]);               \
            wB[3] = relu_pk(acc1[mt][8*q+6], acc1[mt][8*q+7]);               \
            xf1[2*mt+q] = wB;                                                \
        }                                                                    \
    }                                                                        \
} while (0)

// ---------------- fused dual-MLP kernel ----------------
// 128 thr = 2 waves/block, 64 points/wave (pt=2), grid 2048. 1 wave/SIMD.
__launch_bounds__(128, 1)
__global__ void mlp_kernel(const float* __restrict__ gn, const float* __restrict__ gv,
                           const float* __restrict__ gro, const float* __restrict__ gr0,
                           const f16* __restrict__ wpk, const float* __restrict__ bpk,
                           float* __restrict__ out)
{
    __shared__ u32x4 stage[2][2][512];   // [wave][dbuf][8KB chunk], wave-private

    const int tid  = threadIdx.x;
    const int wv   = tid >> 6;
    const int lane = tid & 63;
    const int l32  = lane & 31;
    const int hi   = lane >> 5;
    const int pA   = blockIdx.x * 128 + wv * 64 + l32;
    const int pB   = pA + 32;

    u32x4* buf0 = &stage[wv][0][0];
    u32x4* buf1 = &stage[wv][1][0];

    // issue net0-L1 chunk0 immediately (hides DMA latency under input processing)
    dma8((const u32x4*)(wpk + L1_OFF), buf0, lane);

    // ---- inputs for both points ----
    u32x4 xdA = {0,0,0,0}, xsA = {0,0,0,0}, xdB = {0,0,0,0}, xsB = {0,0,0,0};
    bool visA = false, visB = false;
    if (hi == 0) {
        {
            float nx = gn[3*pA], ny = gn[3*pA+1], nz = gn[3*pA+2];
            float vx = gv[3*pA], vy = gv[3*pA+1], vz = gv[3*pA+2];
            float ro = gro[pA], rr = gr0[pA];
            float ni = 1.0f / fmaxf(sqrtf(nx*nx + ny*ny + nz*nz), 1e-12f);
            float vi = 1.0f / fmaxf(sqrtf(vx*vx + vy*vy + vz*vz), 1e-12f);
            nx *= ni; ny *= ni; nz *= ni; vx *= vi; vy *= vi; vz *= vi;
            visA = (nx*vx + ny*vy + nz*vz) > 0.0f;
            xdA[0] = pkrtz(nx, ny); xdA[1] = pkrtz(nz, 0.0f);
            xsA[0] = xdA[0];        xsA[1] = pkrtz(nz, vx);
            xsA[2] = pkrtz(vy, vz); xsA[3] = pkrtz(ro, rr);
        }
        {
            float nx = gn[3*pB], ny = gn[3*pB+1], nz = gn[3*pB+2];
            float vx = gv[3*pB], vy = gv[3*pB+1], vz = gv[3*pB+2];
            float ro = gro[pB], rr = gr0[pB];
            float ni = 1.0f / fmaxf(sqrtf(nx*nx + ny*ny + nz*nz), 1e-12f);
            float vi = 1.0f / fmaxf(sqrtf(vx*vx + vy*vy + vz*vz), 1e-12f);
            nx *= ni; ny *= ni; nz *= ni; vx *= vi; vy *= vi; vz *= vi;
            visB = (nx*vx + ny*vy + nz*vz) > 0.0f;
            xdB[0] = pkrtz(nx, ny); xdB[1] = pkrtz(nz, 0.0f);
            xsB[0] = xdB[0];        xsB[1] = pkrtz(nz, vx);
            xsB[2] = pkrtz(vy, vz); xsB[3] = pkrtz(ro, rr);
        }
    }

    f32x16 acc0[8], acc1[8];     // 256 VGPRs (unified VGPR/AGPR)
    u32x4  xf0[16], xf1[16];     // 128 VGPRs

    #pragma unroll 1
    for (int net = 0; net < 2; ++net) {
        const f16*   wp = wpk + net * NET_F16;
        const float* bp = bpk + net * 800;
        const f16x8 xhA = __builtin_bit_cast(f16x8, net ? xsA : xdA);
        const f16x8 xhB = __builtin_bit_cast(f16x8, net ? xsB : xdB);

        // ---------- L0 (fragments straight from L2 cache) ----------
        {
            const u32x4* w0q = (const u32x4*)wp;
            #pragma unroll
            for (int mt = 0; mt < 8; ++mt) {
                const f32x4* b4 = (const f32x4*)(bp + mt * 32 + hi * 16);
                const f32x4 v0 = b4[0], v1 = b4[1], v2 = b4[2], v3 = b4[3];
                f32x16 c;
                #pragma unroll
                for (int j = 0; j < 4; ++j) {
                    c[j] = v0[j]; c[4 + j] = v1[j]; c[8 + j] = v2[j]; c[12 + j] = v3[j];
                }
                const f16x8 a = __builtin_bit_cast(f16x8, w0q[mt * 64 + lane]);
                acc0[mt] = __builtin_amdgcn_mfma_f32_32x32x16_f16(a, xhA, c, 0, 0, 0);
                acc1[mt] = __builtin_amdgcn_mfma_f32_32x32x16_f16(a, xhB, c, 0, 0, 0);
            }
        }
        EPI();

        layer256<true>(wp + L1_OFF, bp + 256, wp + L2_OFF,
                       acc0, acc1, xf0, xf1, buf0, buf1, lane, hi);
        EPI();
        if (net == 0) {
            layer256<true>(wp + L2_OFF, bp + 512, wpk + NET_F16 + L1_OFF,
                           acc0, acc1, xf0, xf1, buf0, buf1, lane, hi);
        } else {
            layer256<false>(wp + L2_OFF, bp + 512, (const f16*)0,
                            acc0, acc1, xf0, xf1, buf0, buf1, lane, hi);
        }
        EPI();

        // ---------- L3: 256 -> 3 (fragments from L2 cache) ----------
        {
            const f32x4* b4 = (const f32x4*)(bp + 768 + hi * 16);
            const f32x4 v0 = b4[0], v1 = b4[1], v2 = b4[2], v3 = b4[3];
            f32x16 c0, c1;
            #pragma unroll
            for (int j = 0; j < 4; ++j) {
                c0[j] = v0[j]; c0[4 + j] = v1[j]; c0[8 + j] = v2[j]; c0[12 + j] = v3[j];
                c1[j] = v0[j]; c1[4 + j] = v1[j]; c1[8 + j] = v2[j]; c1[12 + j] = v3[j];
            }
            const u32x4* w3q = (const u32x4*)(wp + L3_OFF);
            #pragma unroll
            for (int kt = 0; kt < 16; ++kt) {
                const f16x8 a = __builtin_bit_cast(f16x8, w3q[kt * 64 + lane]);
                c0 = __builtin_amdgcn_mfma_f32_32x32x16_f16(a, __builtin_bit_cast(f16x8, xf0[kt]), c0, 0, 0, 0);
                c1 = __builtin_amdgcn_mfma_f32_32x32x16_f16(a, __builtin_bit_cast(f16x8, xf1[kt]), c1, 0, 0, 0);
            }
            if (hi == 0) {
                float* opA = out + net * (NPTS * 3) + pA * 3;
                float* opB = out + net * (NPTS * 3) + pB * 3;
                opA[0] = visA ? c0[0] : 0.0f;
                opA[1] = visA ? c0[1] : 0.0f;
                opA[2] = visA ? c0[2] : 0.0f;
                opB[0] = visB ? c1[0] : 0.0f;
                opB[1] = visB ? c1[1] : 0.0f;
                opB[2] = visB ? c1[2] : 0.0f;
            }
        }
    }
}

extern "C" void kernel_launch(void* const* d_in, const int* in_sizes, int n_in,
                              void* d_out, int out_size, void* d_ws, size_t ws_size,
                              hipStream_t stream)
{
    f16*   wpk = (f16*)d_ws;
    float* bpk = (float*)((char*)d_ws + BIAS_BYTE);

    prep_kernel<<<147, 256, 0, stream>>>(
        (const float*)d_in[4],  (const float*)d_in[5],
        (const float*)d_in[6],  (const float*)d_in[7],
        (const float*)d_in[8],  (const float*)d_in[9],
        (const float*)d_in[10], (const float*)d_in[11],
        (const float*)d_in[12], (const float*)d_in[13],
        (const float*)d_in[14], (const float*)d_in[15],
        (const float*)d_in[16], (const float*)d_in[17],
        (const float*)d_in[18], (const float*)d_in[19],
        wpk, bpk);

    mlp_kernel<<<2048, 128, 0, stream>>>(
        (const float*)d_in[0], (const float*)d_in[1],
        (const float*)d_in[2], (const float*)d_in[3],
        wpk, bpk, (float*)d_out);
}

// Round 5
// 213.283 us; speedup vs baseline: 1.0356x; 1.0356x over previous
//
#include <hip/hip_runtime.h>

typedef _Float16 f16;
typedef _Float16 f16x8 __attribute__((ext_vector_type(8)));
typedef __fp16   fp16x2 __attribute__((ext_vector_type(2)));
typedef float    f32x16 __attribute__((ext_vector_type(16)));
typedef float    f32x4  __attribute__((ext_vector_type(4)));
typedef unsigned int u32;
typedef unsigned int u32x4 __attribute__((ext_vector_type(4)));

#define NPTS 262144

// ---- packed layout in d_ws (per net, net stride NET_F16 f16) ----
//   L0:   [0      .. 4096)   frag[mt][lane][8]   canonical k = 8*hi+j (K padded, zeros)
//   L1:   [4096   .. 69632)  frag[kt][mt][lane][8]  PERMUTED k (see kphys below)
//   L2:   [69632  .. 135168) frag[kt][mt][lane][8]  PERMUTED k
//   L3:   [135168 .. 143360) frag[kt][lane][8]      PERMUTED k (m = lane&31 < 3)
// PERMUTED k mapping: kphys(kt,hi,j) = 32*(kt>>1) + 16*(kt&1) + (j&3) + 8*(j>>2) + 4*hi
// == C/D layout of the previous layer's 32x32 tile -> epilogue needs NO cross-lane ops.
// f32 biases at byte BIAS_BYTE, 800 floats/net, packed in C/D order.
#define NET_F16   143360
#define L1_OFF    4096
#define L2_OFF    69632
#define L3_OFF    135168
#define BIAS_BYTE 573440

static __device__ __forceinline__ u32 pkrtz(float a, float b) {
    fp16x2 h = __builtin_amdgcn_cvt_pkrtz(a, b);
    return __builtin_bit_cast(u32, h);
}
static __device__ __forceinline__ u32 relu_pk(float a, float b) {
    return pkrtz(fmaxf(a, 0.0f), fmaxf(b, 0.0f));
}

// ---------------- weight/bias packing kernel ----------------
__global__ void prep_kernel(
    const float* __restrict__ dW0, const float* __restrict__ db0,
    const float* __restrict__ dW1, const float* __restrict__ db1,
    const float* __restrict__ dW2, const float* __restrict__ db2,
    const float* __restrict__ dW3, const float* __restrict__ db3,
    const float* __restrict__ sW0, const float* __restrict__ sb0,
    const float* __restrict__ sW1, const float* __restrict__ sb1,
    const float* __restrict__ sW2, const float* __restrict__ sb2,
    const float* __restrict__ sW3, const float* __restrict__ sb3,
    f16* __restrict__ wpk, float* __restrict__ bpk)
{
    const int ROWS = 17920;
    int t = blockIdx.x * 256 + threadIdx.x;
    if (t < 2 * ROWS) {
        int net = (t >= ROWS) ? 1 : 0;
        int r = t - net * ROWS;
        const float* W0 = net ? sW0 : dW0;
        const float* W1 = net ? sW1 : dW1;
        const float* W2 = net ? sW2 : dW2;
        const float* W3 = net ? sW3 : dW3;
        int K0 = net ? 8 : 3;
        f16* o = wpk + net * NET_F16;
        if (r < 512) {                                   // L0: canonical slots
            int lane = r & 63;
            int m  = 32 * (r >> 6) + (lane & 31);
            int kb = 8 * (lane >> 5);
            f16* q = o + r * 8;
            #pragma unroll
            for (int j = 0; j < 8; ++j) {
                int k = kb + j;
                q[j] = (f16)((k < K0) ? W0[k * 256 + m] : 0.0f);
            }
        } else if (r < 512 + 8192) {                     // L1: permuted k
            int rr = r - 512;
            int lane = rr & 63;
            int hh = lane >> 5;
            int m  = 32 * ((rr >> 6) & 7) + (lane & 31);
            int kt = rr >> 9;
            f16* q = o + L1_OFF + rr * 8;
            #pragma unroll
            for (int j = 0; j < 8; ++j) {
                int kp = 32 * (kt >> 1) + 16 * (kt & 1) + (j & 3) + 8 * (j >> 2) + 4 * hh;
                q[j] = (f16)W1[kp * 256 + m];
            }
        } else if (r < 512 + 16384) {                    // L2: permuted k
            int rr = r - (512 + 8192);
            int lane = rr & 63;
            int hh = lane >> 5;
            int m  = 32 * ((rr >> 6) & 7) + (lane & 31);
            int kt = rr >> 9;
            f16* q = o + L2_OFF + rr * 8;
            #pragma unroll
            for (int j = 0; j < 8; ++j) {
                int kp = 32 * (kt >> 1) + 16 * (kt & 1) + (j & 3) + 8 * (j >> 2) + 4 * hh;
                q[j] = (f16)W2[kp * 256 + m];
            }
        } else {                                         // L3: permuted k
            int rr = r - (512 + 16384);
            int lane = rr & 63;
            int hh = lane >> 5;
            int m  = lane & 31;
            int kt = rr >> 6;
            f16* q = o + L3_OFF + rr * 8;
            #pragma unroll
            for (int j = 0; j < 8; ++j) {
                int kp = 32 * (kt >> 1) + 16 * (kt & 1) + (j & 3) + 8 * (j >> 2) + 4 * hh;
                q[j] = (f16)((m < 3) ? W3[kp * 3 + m] : 0.0f);
            }
        }
    } else if (t < 2 * ROWS + 1600) {                    // biases (C/D order)
        int tb = t - 2 * ROWS;
        int net = (tb >= 800) ? 1 : 0;
        int i = tb - net * 800;
        float val;
        if (i < 768) {
            int layer = i >> 8;
            const float* bl = net ? (layer == 0 ? sb0 : layer == 1 ? sb1 : sb2)
                                  : (layer == 0 ? db0 : layer == 1 ? db1 : db2);
            int q  = i & 255;
            int rg = q & 15, h = (q >> 4) & 1;
            int m  = 32 * (q >> 5) + (rg & 3) + 8 * (rg >> 2) + 4 * h;
            val = bl[m];
        } else {
            int q  = i - 768;
            int rg = q & 15, h = q >> 4;
            int m  = (rg & 3) + 8 * (rg >> 2) + 4 * h;
            const float* b3 = net ? sb3 : db3;
            val = (m < 3) ? b3[m] : 0.0f;
        }
        bpk[net * 800 + i] = val;
    }
}

// 8 x global_load_lds dwordx4: one 8KB weight chunk (frag[mt][lane], lane-linear).
static __device__ __forceinline__ void dma8(const u32x4* __restrict__ g, u32x4* l, int lane) {
    #pragma unroll
    for (int i = 0; i < 8; ++i)
        __builtin_amdgcn_global_load_lds(
            (const __attribute__((address_space(1))) void*)(g + i * 64 + lane),
            (__attribute__((address_space(3))) void*)(l + i * 64), 16, 0, 0);
}

// 256x256 layer, pt=1: wave-private dbuf, counted vmcnt, NO barriers.
template<bool HASNXT>
static __device__ __forceinline__ void layer256(
    const f16* __restrict__ wl, const float* __restrict__ bl, const f16* __restrict__ nxt,
    f32x16 (&acc)[8], u32x4 (&xf)[16],
    u32x4* buf0, u32x4* buf1, const int lane, const int hi)
{
    const u32x4* wq = (const u32x4*)wl;
    #pragma unroll
    for (int mt = 0; mt < 8; ++mt) {                     // bias-init acc
        const f32x4* b4 = (const f32x4*)(bl + mt * 32 + hi * 16);
        const f32x4 v0 = b4[0], v1 = b4[1], v2 = b4[2], v3 = b4[3];
        #pragma unroll
        for (int j = 0; j < 4; ++j) {
            acc[mt][j] = v0[j]; acc[mt][4 + j] = v1[j];
            acc[mt][8 + j] = v2[j]; acc[mt][12 + j] = v3[j];
        }
    }
    #pragma unroll
    for (int kt = 0; kt < 16; ++kt) {
        if (kt < 15) {                                   // issue next chunk early
            dma8(wq + (kt + 1) * 512, (kt & 1) ? buf0 : buf1, lane);
            asm volatile("s_waitcnt vmcnt(8)" ::: "memory");   // chunk kt landed (in-order)
        } else if (HASNXT) {                             // chain next layer's chunk0
            dma8((const u32x4*)nxt, buf0, lane);
            asm volatile("s_waitcnt vmcnt(8)" ::: "memory");
        } else {
            asm volatile("s_waitcnt vmcnt(0)" ::: "memory");
        }
        const u32x4* src = (kt & 1) ? buf1 : buf0;
        const f16x8 xh = __builtin_bit_cast(f16x8, xf[kt]);
        #pragma unroll
        for (int mt = 0; mt < 8; ++mt) {
            const f16x8 a = __builtin_bit_cast(f16x8, src[mt * 64 + lane]);
            acc[mt] = __builtin_amdgcn_mfma_f32_32x32x16_f16(a, xh, acc[mt], 0, 0, 0);
        }
    }
}

// Zero-shuffle epilogue: C/D regs -> ReLU -> f16 -> next-layer B-frags in place.
#define EPI() do {                                                           \
    _Pragma("unroll")                                                        \
    for (int mt = 0; mt < 8; ++mt) {                                         \
        _Pragma("unroll")                                                    \
        for (int q = 0; q < 2; ++q) {                                        \
            u32x4 w;                                                         \
            w[0] = relu_pk(acc[mt][8*q+0], acc[mt][8*q+1]);                  \
            w[1] = relu_pk(acc[mt][8*q+2], acc[mt][8*q+3]);                  \
            w[2] = relu_pk(acc[mt][8*q+4], acc[mt][8*q+5]);                  \
            w[3] = relu_pk(acc[mt][8*q+6], acc[mt][8*q+7]);                  \
            xf[2*mt+q] = w;                                                  \
        }                                                                    \
    }                                                                        \
} while (0)

// ---------------- fused dual-MLP kernel ----------------
// 256 thr = 4 waves/block, 32 points/wave (pt=1), grid 2048, 2 blocks/CU,
// 2 waves/SIMD. Waves fully independent: NO __syncthreads in the kernel.
__launch_bounds__(256, 2)
__global__ void mlp_kernel(const float* __restrict__ gn, const float* __restrict__ gv,
                           const float* __restrict__ gro, const float* __restrict__ gr0,
                           const f16* __restrict__ wpk, const float* __restrict__ bpk,
                           float* __restrict__ out)
{
    __shared__ u32x4 stage[4][2][512];   // [wave][dbuf][8KB], wave-private = 64KB

    const int tid  = threadIdx.x;
    const int wv   = tid >> 6;
    const int lane = tid & 63;
    const int l32  = lane & 31;
    const int hi   = lane >> 5;
    const int p    = blockIdx.x * 128 + wv * 32 + l32;

    u32x4* buf0 = &stage[wv][0][0];
    u32x4* buf1 = &stage[wv][1][0];

    // issue net0-L1 chunk0 immediately (hides DMA latency under input processing)
    dma8((const u32x4*)(wpk + L1_OFF), buf0, lane);

    // ---- inputs ----
    u32x4 xd = {0,0,0,0}, xs = {0,0,0,0};
    bool vis = false;
    if (hi == 0) {               // hi lanes hold k=8..15 (zero-padded)
        float nx = gn[3*p], ny = gn[3*p+1], nz = gn[3*p+2];
        float vx = gv[3*p], vy = gv[3*p+1], vz = gv[3*p+2];
        float ro = gro[p], rr = gr0[p];
        float ni = 1.0f / fmaxf(sqrtf(nx*nx + ny*ny + nz*nz), 1e-12f);
        float vi = 1.0f / fmaxf(sqrtf(vx*vx + vy*vy + vz*vz), 1e-12f);
        nx *= ni; ny *= ni; nz *= ni; vx *= vi; vy *= vi; vz *= vi;
        vis = (nx*vx + ny*vy + nz*vz) > 0.0f;
        xd[0] = pkrtz(nx, ny); xd[1] = pkrtz(nz, 0.0f);
        xs[0] = xd[0];         xs[1] = pkrtz(nz, vx);
        xs[2] = pkrtz(vy, vz); xs[3] = pkrtz(ro, rr);
    }

    f32x16 acc[8];    // 128 regs (AGPR-eligible C/D)
    u32x4  xf[16];    // 64 regs

    #pragma unroll 1
    for (int net = 0; net < 2; ++net) {
        const f16*   wp = wpk + net * NET_F16;
        const float* bp = bpk + net * 800;
        const f16x8 xh0 = __builtin_bit_cast(f16x8, net ? xs : xd);

        // ---------- L0 (fragments straight from L2 cache) ----------
        {
            const u32x4* w0q = (const u32x4*)wp;
            #pragma unroll
            for (int mt = 0; mt < 8; ++mt) {
                const f32x4* b4 = (const f32x4*)(bp + mt * 32 + hi * 16);
                const f32x4 v0 = b4[0], v1 = b4[1], v2 = b4[2], v3 = b4[3];
                f32x16 c;
                #pragma unroll
                for (int j = 0; j < 4; ++j) {
                    c[j] = v0[j]; c[4 + j] = v1[j]; c[8 + j] = v2[j]; c[12 + j] = v3[j];
                }
                const f16x8 a = __builtin_bit_cast(f16x8, w0q[mt * 64 + lane]);
                acc[mt] = __builtin_amdgcn_mfma_f32_32x32x16_f16(a, xh0, c, 0, 0, 0);
            }
        }
        EPI();

        layer256<true>(wp + L1_OFF, bp + 256, wp + L2_OFF,
                       acc, xf, buf0, buf1, lane, hi);
        EPI();
        if (net == 0) {
            layer256<true>(wp + L2_OFF, bp + 512, wpk + NET_F16 + L1_OFF,
                           acc, xf, buf0, buf1, lane, hi);
        } else {
            layer256<false>(wp + L2_OFF, bp + 512, (const f16*)0,
                            acc, xf, buf0, buf1, lane, hi);
        }
        EPI();

        // ---------- L3: 256 -> 3 (fragments from L2 cache) ----------
        {
            const f32x4* b4 = (const f32x4*)(bp + 768 + hi * 16);
            const f32x4 v0 = b4[0], v1 = b4[1], v2 = b4[2], v3 = b4[3];
            f32x16 c;
            #pragma unroll
            for (int j = 0; j < 4; ++j) {
                c[j] = v0[j]; c[4 + j] = v1[j]; c[8 + j] = v2[j]; c[12 + j] = v3[j];
            }
            const u32x4* w3q = (const u32x4*)(wp + L3_OFF);
            #pragma unroll
            for (int kt = 0; kt < 16; ++kt) {
                const f16x8 a = __builtin_bit_cast(f16x8, w3q[kt * 64 + lane]);
                c = __builtin_amdgcn_mfma_f32_32x32x16_f16(
                        a, __builtin_bit_cast(f16x8, xf[kt]), c, 0, 0, 0);
            }
            if (hi == 0) {
                float* op = out + net * (NPTS * 3) + p * 3;
                op[0] = vis ? c[0] : 0.0f;
                op[1] = vis ? c[1] : 0.0f;
                op[2] = vis ? c[2] : 0.0f;
            }
        }
    }
}

extern "C" void kernel_launch(void* const* d_in, const int* in_sizes, int n_in,
                              void* d_out, int out_size, void* d_ws, size_t ws_size,
                              hipStream_t stream)
{
    f16*   wpk = (f16*)d_ws;
    float* bpk = (float*)((char*)d_ws + BIAS_BYTE);

    prep_kernel<<<147, 256, 0, stream>>>(
        (const float*)d_in[4],  (const float*)d_in[5],
        (const float*)d_in[6],  (const float*)d_in[7],
        (const float*)d_in[8],  (const float*)d_in[9],
        (const float*)d_in[10], (const float*)d_in[11],
        (const float*)d_in[12], (const float*)d_in[13],
        (const float*)d_in[14], (const float*)d_in[15],
        (const float*)d_in[16], (const float*)d_in[17],
        (const float*)d_in[18], (const float*)d_in[19],
        wpk, bpk);

    mlp_kernel<<<2048, 256, 0, stream>>>(
        (const float*)d_in[0], (const float*)d_in[1],
        (const float*)d_in[2], (const float*)d_in[3],
        wpk, bpk, (float*)d_out);
}